// Round 25
// baseline (1853.756 us; speedup 1.0000x reference)
//
#include <hip/hip_runtime.h>
#include <hip/hip_bf16.h>
#include <math.h>

#define MQ      1024
#define NTRAIN  200000
#define NT256   782             // N-tiles of 256
#define KDIM    768
#define NPAN    12              // K-panels of 64
#define PANB    16384           // bytes per 256-row x 64-k fp8 panel
#define NCLS    1000
#define CAP     1024
#define DELTA   16.0f
#define KSEL    32
#define TINV    (1.0f/0.07f)

typedef short s16x8  __attribute__((ext_vector_type(8)));
typedef int   i32x4  __attribute__((ext_vector_type(4)));
typedef int   i32x8  __attribute__((ext_vector_type(8)));
typedef float f32x4  __attribute__((ext_vector_type(4)));
typedef float f32x16 __attribute__((ext_vector_type(16)));

__device__ __forceinline__ unsigned encf(float x){
    unsigned u = __float_as_uint(x);
    return (u & 0x80000000u) ? ~u : (u | 0x80000000u);
}
__device__ __forceinline__ float decf(unsigned e){
    unsigned u = (e & 0x80000000u) ? (e & 0x7FFFFFFFu) : ~e;
    return __uint_as_float(u);
}
__device__ __forceinline__ ushort cvt_bf16(float x){
    unsigned u = __float_as_uint(x);
    u += 0x7FFFu + ((u >> 16) & 1u);
    return (ushort)(u >> 16);
}
__device__ __forceinline__ void gload_lds16(const void* g, void* l){
    __builtin_amdgcn_global_load_lds(
        (const __attribute__((address_space(1))) unsigned int*)g,
        (__attribute__((address_space(3))) unsigned int*)l, 16, 0, 0);
}
// MX-scaled fp8 MFMA, formats A=B=e4m3 (0), all scales = 1.0 (E8M0 127).
__device__ __forceinline__ f32x16 mfma_fp8(i32x8 a, i32x8 b, f32x16 c){
    return __builtin_amdgcn_mfma_scale_f32_32x32x64_f8f6f4(
        a, b, c, 0, 0, 0, 0x7F7F7F7Fu, 0, 0x7F7F7F7Fu);
}

#define VMWAIT(N) asm volatile("s_waitcnt vmcnt(" #N ")" ::: "memory")
#define RBAR()    asm volatile("s_barrier" ::: "memory")
#define SBAR()    __builtin_amdgcn_sched_barrier(0)
#define PRIO1()   __builtin_amdgcn_s_setprio(1)
#define PRIO0()   __builtin_amdgcn_s_setprio(0)

__global__ void init_kernel(unsigned* rowMaxBits, int* counts){
    int i = blockIdx.x * blockDim.x + threadIdx.x;
    if (i < MQ){ rowMaxBits[i] = 0u; counts[i] = 0; }
}

// fp32 -> fp8(e4m3), SPLIT-FRAGMENT layout (bank-conflict-free reads).
// Panel = 256 rows x 64 k = 8 rowblocks x 2048 B. Element (r,k):
// byte = (r>>5)*2048 + ((k>>4)&1)*1024 + ((k>>5)*32 + (r&31))*16 + (k&15).
// Lane l of a fragment reads 16 B at rowblock*2048 + l*16 and 16 B at
// +1024 + l*16: contiguous 1024-B wave reads -> zero conflicts.
__launch_bounds__(256)
__global__ void convert_tile_kernel(const float* __restrict__ Aq,
                                    const float* __restrict__ Bt,
                                    char* __restrict__ Af8,
                                    char* __restrict__ Bf8){
    const int bid = blockIdx.x;            // (4 + 782) * 24 half-panels
    const int rt  = bid / 24;
    const int kh  = bid - rt * 24;         // 0..23
    const int pan  = kh >> 1;
    const int half = kh & 1;               // khalf (32 k)
    const int tid = threadIdx.x;

    const float* src; char* dst; int rowBase, nRows;
    if (rt < 4){
        src = Aq; dst = Af8 + ((size_t)rt * NPAN + pan) * PANB;
        rowBase = rt * 256; nRows = MQ;
    } else {
        src = Bt; dst = Bf8 + ((size_t)(rt - 4) * NPAN + pan) * PANB;
        rowBase = (rt - 4) * 256; nRows = NTRAIN;
    }

    __shared__ unsigned tile[2048];   // 8 KB

    #pragma unroll
    for (int i = 0; i < 8; ++i){
        int idx = i * 256 + tid;           // float4 unit, 0..2047
        int r   = idx >> 3;                // 0..255
        int c4  = idx & 7;                 // float4 col within 32-k half
        int grow = rowBase + r;
        float4 v = make_float4(0.f, 0.f, 0.f, 0.f);
        if (grow < nRows)
            v = *reinterpret_cast<const float4*>(
                src + (size_t)grow * KDIM + pan * 64 + half * 32 + c4 * 4);
        int p = 0;
        p = __builtin_amdgcn_cvt_pk_fp8_f32(v.x, v.y, p, false);
        p = __builtin_amdgcn_cvt_pk_fp8_f32(v.z, v.w, p, true);
        int word = (r >> 5) * 256 + (c4 >> 2) * 128 + (r & 31) * 4 + (c4 & 3);
        tile[word] = (unsigned)p;
    }
    __syncthreads();
    #pragma unroll
    for (int i = 0; i < 2; ++i){
        int c = i * 256 + tid;             // 16B chunk, 0..511
        int rowblock = c >> 6, rem = c & 63, jh = rem >> 5, row = rem & 31;
        size_t off = (size_t)rowblock * 2048 + (size_t)jh * 1024
                   + (size_t)half * 512 + (size_t)row * 16;
        *reinterpret_cast<i32x4*>(dst + off) =
            *reinterpret_cast<const i32x4*>((const char*)tile + c * 16);
    }
}

// 256x256 tile, 16 waves (4 wr x 4 wc, per-wave 64x64 -> acc 64 regs),
// TWO LDS buffers (64 KB) -> 2 BLOCKS/CU = 8 waves/SIMD. Live set ~115
// fits the 256-reg cap the 2-block grant imposes (unlike the 128-reg-acc
// configs that spilled). Depth-1 schedule: stage(t+1) during panel t,
// one VMWAIT(0)+RBAR per panel; cross-block TLP covers the drain.
__launch_bounds__(1024)
__global__ void gemm_fast_kernel(const char* __restrict__ Af8,
                                 const char* __restrict__ Bf8,
                                 unsigned* __restrict__ rowMaxBits,
                                 int* __restrict__ counts,
                                 int* __restrict__ cands){
    const int g    = blockIdx.x;                 // 3128 = 8 * 391
    const int wgid = (g & 7) * 391 + (g >> 3);   // bijective XCD chunking
    const int mt   = wgid & 3;
    const int nt   = wgid >> 2;
    const int tid  = threadIdx.x;
    const int lane = tid & 63;
    const int wave = tid >> 6;       // 0..15
    const int wr   = wave >> 2;      // 0..3  rows wr*64
    const int wc   = wave & 3;       // 0..3  cols wc*64
    const int lh   = lane >> 5;
    const int lm   = lane & 31;

    __shared__ union {
        char stg[2][2][PANB];                         // 64 KB staging
        struct { float redmax[256][4]; float ths[256]; } ep;
    } sm;

    const char* Apan = Af8 + (size_t)mt * NPAN * PANB;
    const char* Bpan = Bf8 + (size_t)nt * NPAN * PANB;

    f32x16 acc[2][2];
    #pragma unroll
    for (int i = 0; i < 2; ++i)
        #pragma unroll
        for (int j = 0; j < 2; ++j)
            #pragma unroll
            for (int q = 0; q < 16; ++q)
                acc[i][j][q] = 0.f;

    i32x8 aq0, aq1, bq0, bq1;

    auto stageAB = [&](int t){
        const char* sa = Apan + (size_t)t * PANB;
        const char* sb = Bpan + (size_t)t * PANB;
        char* da = &sm.stg[t & 1][0][0];
        char* db = &sm.stg[t & 1][1][0];
        gload_lds16(sa + tid * 16, da + tid * 16);   // A: 1024 chunks
        gload_lds16(sb + tid * 16, db + tid * 16);   // B: 1024 chunks
    };

#define LD_FRAG(V, AB, T, F) { \
    const char* b_ = &sm.stg[(T) & 1][AB][(F) * 2048]; \
    i32x4 lo_ = *reinterpret_cast<const i32x4*>(b_ + lane * 16); \
    i32x4 hi_ = *reinterpret_cast<const i32x4*>(b_ + 1024 + lane * 16); \
    V = __builtin_shufflevector(lo_, hi_, 0, 1, 2, 3, 4, 5, 6, 7); }

#define PANEL(T, STAGE, WAITCODE) { \
    LD_FRAG(bq0, 1, T, wc * 2 + 0); \
    LD_FRAG(bq1, 1, T, wc * 2 + 1); \
    LD_FRAG(aq0, 0, T, wr * 2 + 0); \
    LD_FRAG(aq1, 0, T, wr * 2 + 1); \
    STAGE; \
    SBAR(); \
    PRIO1(); \
    acc[0][0] = mfma_fp8(aq0, bq0, acc[0][0]); \
    acc[0][1] = mfma_fp8(aq0, bq1, acc[0][1]); \
    acc[1][0] = mfma_fp8(aq1, bq0, acc[1][0]); \
    acc[1][1] = mfma_fp8(aq1, bq1, acc[1][1]); \
    PRIO0(); SBAR(); \
    WAITCODE; }

    // prologue: panel 0 staged and drained
    stageAB(0);
    VMWAIT(0);
    RBAR();

    #pragma unroll 2
    for (int t = 0; t < NPAN - 1; ++t){
        PANEL(t, stageAB(t + 1), { VMWAIT(0); RBAR(); });
    }
    PANEL(NPAN - 1, (void)0, (void)0);
#undef PANEL
#undef LD_FRAG

    // ---- epilogue: cross-wc row-max reduce, 1 atomicMax/row, collect ----
    __syncthreads();
    #pragma unroll
    for (int rf = 0; rf < 2; ++rf)
        #pragma unroll
        for (int q = 0; q < 16; ++q){
            float v = fmaxf(acc[rf][0][q], acc[rf][1][q]);
            v = fmaxf(v, __shfl_xor(v, 1));
            v = fmaxf(v, __shfl_xor(v, 2));
            v = fmaxf(v, __shfl_xor(v, 4));
            v = fmaxf(v, __shfl_xor(v, 8));
            v = fmaxf(v, __shfl_xor(v, 16));
            if (lm == 0){
                int row = wr * 64 + rf * 32 + (q & 3) + 8 * (q >> 2) + 4 * lh;
                sm.ep.redmax[row][wc] = v;
            }
        }
    __syncthreads();
    if (tid < 256){
        float m = fmaxf(fmaxf(sm.ep.redmax[tid][0], sm.ep.redmax[tid][1]),
                        fmaxf(sm.ep.redmax[tid][2], sm.ep.redmax[tid][3]));
        unsigned old = atomicMax(&rowMaxBits[mt * 256 + tid], encf(m));
        sm.ep.ths[tid] = fmaxf(m, decf(old)) - DELTA;
    }
    __syncthreads();
    #pragma unroll
    for (int rf = 0; rf < 2; ++rf)
        #pragma unroll
        for (int q = 0; q < 16; ++q){
            int row = wr * 64 + rf * 32 + (q & 3) + 8 * (q >> 2) + 4 * lh;
            float thr = sm.ep.ths[row];
            #pragma unroll
            for (int cf = 0; cf < 2; ++cf){
                if (acc[rf][cf][q] >= thr){
                    int gcol = nt * 256 + wc * 64 + cf * 32 + lm;
                    if (gcol < NTRAIN){
                        int grow = mt * 256 + row;
                        int slot = atomicAdd(&counts[grow], 1);
                        if (slot < CAP) cands[(size_t)grow * CAP + slot] = gcol;
                    }
                }
            }
        }
}

// ---- fallback GEMM (round-0 path, used only if ws too small) ----
__launch_bounds__(256)
__global__ void gemm_collect_kernel(const float* __restrict__ Aq,
                                    const float* __restrict__ Bt,
                                    unsigned* __restrict__ rowMaxBits,
                                    int* __restrict__ counts,
                                    int* __restrict__ cands){
    const int m0 = blockIdx.x * 128;
    const int n0 = blockIdx.y * 128;
    const int tid  = threadIdx.x;
    const int lane = tid & 63;
    const int wave = tid >> 6;
    const int wm = (wave >> 1) * 64;
    const int wn = (wave & 1) * 64;

    __shared__ union {
        struct { ushort As[128][32]; ushort Bs[128][32]; } s;
        float Csh[64][129];
    } sm;

    f32x4 acc[4][4];
    #pragma unroll
    for (int i = 0; i < 4; ++i)
        #pragma unroll
        for (int j = 0; j < 4; ++j)
            acc[i][j] = (f32x4){0.f, 0.f, 0.f, 0.f};

    const int fr = lane & 15;
    const int fg = lane >> 4;

    for (int kt = 0; kt < KDIM / 32; ++kt){
        const int k0 = kt * 32;
        __syncthreads();
        #pragma unroll
        for (int i = 0; i < 4; ++i){
            int f  = tid + i * 256;
            int r  = f >> 3;
            int kc = (f & 7) * 4;
            float4 av = *reinterpret_cast<const float4*>(Aq + (size_t)(m0 + r) * KDIM + k0 + kc);
            ushort4 ah; ah.x = cvt_bf16(av.x); ah.y = cvt_bf16(av.y);
            ah.z = cvt_bf16(av.z); ah.w = cvt_bf16(av.w);
            *reinterpret_cast<ushort4*>(&sm.s.As[r][kc]) = ah;
            int nr = n0 + r;
            float4 bv = make_float4(0.f, 0.f, 0.f, 0.f);
            if (nr < NTRAIN)
                bv = *reinterpret_cast<const float4*>(Bt + (size_t)nr * KDIM + k0 + kc);
            ushort4 bh; bh.x = cvt_bf16(bv.x); bh.y = cvt_bf16(bv.y);
            bh.z = cvt_bf16(bv.z); bh.w = cvt_bf16(bv.w);
            *reinterpret_cast<ushort4*>(&sm.s.Bs[r][kc]) = bh;
        }
        __syncthreads();
        s16x8 af[4], bfv[4];
        #pragma unroll
        for (int i = 0; i < 4; ++i){
            af[i]  = *reinterpret_cast<const s16x8*>(&sm.s.As[wm + i * 16 + fr][fg * 8]);
            bfv[i] = *reinterpret_cast<const s16x8*>(&sm.s.Bs[wn + i * 16 + fr][fg * 8]);
        }
        #pragma unroll
        for (int i = 0; i < 4; ++i)
            #pragma unroll
            for (int j = 0; j < 4; ++j)
                acc[i][j] = __builtin_amdgcn_mfma_f32_16x16x32_bf16(af[i], bfv[j], acc[i][j], 0, 0, 0);
    }

    for (int half = 0; half < 2; ++half){
        __syncthreads();
        if ((wave >> 1) == half){
            #pragma unroll
            for (int i = 0; i < 4; ++i)
                #pragma unroll
                for (int j = 0; j < 4; ++j)
                    #pragma unroll
                    for (int q = 0; q < 4; ++q){
                        int rr = i * 16 + (lane >> 4) * 4 + q;
                        int cc = wn + j * 16 + (lane & 15);
                        sm.Csh[rr][cc] = acc[i][j][q];
                    }
        }
        __syncthreads();
        if (tid < 64){
            int grow = m0 + half * 64 + tid;
            float mx = -1e30f;
            #pragma unroll 4
            for (int c = 0; c < 128; ++c) mx = fmaxf(mx, sm.Csh[tid][c]);
            unsigned old = atomicMax(&rowMaxBits[grow], encf(mx));
            float gmax = fmaxf(mx, decf(old));
            float thr = gmax - DELTA;
            for (int c = 0; c < 128; ++c){
                int gcol = n0 + c;
                if (gcol < NTRAIN && sm.Csh[tid][c] >= thr){
                    int slot = atomicAdd(&counts[grow], 1);
                    if (slot < CAP) cands[(size_t)grow * CAP + slot] = gcol;
                }
            }
        }
    }
}

// one block per query row: exact fp32 rescore, top-KSEL, softmax, output.
__launch_bounds__(256)
__global__ void rescore_output_kernel(const float* __restrict__ Aq,
                                      const float* __restrict__ Bt,
                                      const int* __restrict__ labels,
                                      const int* __restrict__ counts,
                                      const int* __restrict__ cands,
                                      float* __restrict__ out){
    const int row  = blockIdx.x;
    const int tid  = threadIdx.x;
    const int lane = tid & 63;
    const int wave = tid >> 6;

    __shared__ float q[KDIM];
    __shared__ float sv[CAP];
    __shared__ float rv[256];
    __shared__ int   ri[256];
    __shared__ float topS[KSEL];
    __shared__ int   topI[KSEL];
    __shared__ float cls[3][NCLS];

    for (int k = tid; k < KDIM; k += 256) q[k] = Aq[(size_t)row * KDIM + k];
    int m = counts[row]; if (m > CAP) m = CAP;
    __syncthreads();

    for (int c = wave; c < m; c += 4){
        int idx = cands[(size_t)row * CAP + c];
        const float* b = Bt + (size_t)idx * KDIM;
        float s = 0.f;
        #pragma unroll
        for (int u = 0; u < 12; ++u){
            int k = lane * 12 + u;
            s += q[k] * b[k];
        }
        #pragma unroll
        for (int off = 32; off; off >>= 1) s += __shfl_down(s, off);
        if (lane == 0) sv[c] = s;
    }
    __syncthreads();

    int msel = m < KSEL ? m : KSEL;
    for (int j = 0; j < msel; ++j){
        float bs = -1e30f; int bi = 0x7FFFFFFF;
        for (int c = tid; c < m; c += 256){
            float v = sv[c];
            if (v > bs){ bs = v; bi = c; }
        }
        rv[tid] = bs; ri[tid] = bi;
        __syncthreads();
        for (int st = 128; st; st >>= 1){
            if (tid < st){
                if (rv[tid + st] > rv[tid] ||
                    (rv[tid + st] == rv[tid] && ri[tid + st] < ri[tid])){
                    rv[tid] = rv[tid + st]; ri[tid] = ri[tid + st];
                }
            }
            __syncthreads();
        }
        if (tid == 0){
            topS[j] = rv[0];
            topI[j] = cands[(size_t)row * CAP + ri[0]];
            sv[ri[0]] = -1e30f;
        }
        __syncthreads();
    }

    for (int i = tid; i < 3 * NCLS; i += 256) (&cls[0][0])[i] = 0.f;
    __syncthreads();

    if (tid == 0){
        float s0 = topS[0];
        float e[KSEL];
        float Z = 0.f;
        for (int j = 0; j < msel; ++j){ e[j] = __expf((topS[j] - s0) * TINV); Z += e[j]; }
        float inv = 1.f / Z;
        for (int j = 0; j < msel; ++j){
            int lb = labels[topI[j]];
            float w = e[j] * inv;
            if (j < 10) cls[0][lb] += w;
            if (j < 50) cls[1][lb] += w;
            cls[2][lb] += w;
        }
    }
    __syncthreads();

    for (int c = tid; c < NCLS; c += 256){
        out[(size_t)row * NCLS + c]                         = cls[0][c];
        out[(size_t)MQ * NCLS + (size_t)row * NCLS + c]     = cls[1][c];
        out[(size_t)2 * MQ * NCLS + (size_t)row * NCLS + c] = cls[2][c];
    }
}

extern "C" void kernel_launch(void* const* d_in, const int* in_sizes, int n_in,
                              void* d_out, int out_size, void* d_ws, size_t ws_size,
                              hipStream_t stream){
    const float* Aq     = (const float*)d_in[0];
    const float* Bt     = (const float*)d_in[1];
    const int*   labels = (const int*)d_in[2];
    float* out = (float*)d_out;

    char* ws = (char*)d_ws;
    unsigned* rowMaxBits = (unsigned*)ws;                         // MQ u32
    int*      counts     = (int*)(ws + (size_t)MQ * 4);           // MQ i32
    int*      cands      = (int*)(ws + (size_t)MQ * 8);           // MQ*CAP i32
    char*     Af8        = ws + (size_t)MQ * 8 + (size_t)MQ * CAP * 4;
    char*     Bf8        = Af8 + (size_t)4 * NPAN * PANB;

    const size_t need = (size_t)MQ * 8 + (size_t)MQ * CAP * 4
                      + (size_t)(4 + NT256) * NPAN * PANB;

    hipLaunchKernelGGL(init_kernel, dim3(4), dim3(256), 0, stream, rowMaxBits, counts);

    if (ws_size >= need){
        hipLaunchKernelGGL(convert_tile_kernel, dim3((4 + NT256) * 24), dim3(256), 0, stream,
                           Aq, Bt, Af8, Bf8);
        hipLaunchKernelGGL(gemm_fast_kernel, dim3(8 * 391), dim3(1024), 0, stream,
                           Af8, Bf8, rowMaxBits, counts, cands);
    } else {
        hipLaunchKernelGGL(gemm_collect_kernel, dim3(8, (NTRAIN + 127) / 128), dim3(256), 0, stream,
                           Aq, Bt, rowMaxBits, counts, cands);
    }
    hipLaunchKernelGGL(rescore_output_kernel, dim3(MQ), dim3(256), 0, stream,
                       Aq, Bt, labels, counts, cands, out);
}

// Round 26
// 515.473 us; speedup vs baseline: 3.5962x; 3.5962x over previous
//
#include <hip/hip_runtime.h>
#include <hip/hip_bf16.h>
#include <math.h>

#define MQ      1024
#define NTRAIN  200000
#define NT256   782             // N-tiles of 256
#define KDIM    768
#define NPAN    12              // K-panels of 64
#define PANB    16384           // bytes per 256-row x 64-k fp8 panel
#define NCLS    1000
#define CAP     1024
#define DELTA   16.0f
#define KSEL    32
#define TINV    (1.0f/0.07f)

typedef short s16x8  __attribute__((ext_vector_type(8)));
typedef int   i32x4  __attribute__((ext_vector_type(4)));
typedef int   i32x8  __attribute__((ext_vector_type(8)));
typedef float f32x4  __attribute__((ext_vector_type(4)));
typedef float f32x16 __attribute__((ext_vector_type(16)));

__device__ __forceinline__ unsigned encf(float x){
    unsigned u = __float_as_uint(x);
    return (u & 0x80000000u) ? ~u : (u | 0x80000000u);
}
__device__ __forceinline__ float decf(unsigned e){
    unsigned u = (e & 0x80000000u) ? (e & 0x7FFFFFFFu) : ~e;
    return __uint_as_float(u);
}
__device__ __forceinline__ ushort cvt_bf16(float x){
    unsigned u = __float_as_uint(x);
    u += 0x7FFFu + ((u >> 16) & 1u);
    return (ushort)(u >> 16);
}
__device__ __forceinline__ void gload_lds16(const void* g, void* l){
    __builtin_amdgcn_global_load_lds(
        (const __attribute__((address_space(1))) unsigned int*)g,
        (__attribute__((address_space(3))) unsigned int*)l, 16, 0, 0);
}
// MX-scaled fp8 MFMA, formats A=B=e4m3 (0), all scales = 1.0 (E8M0 127).
__device__ __forceinline__ f32x16 mfma_fp8(i32x8 a, i32x8 b, f32x16 c){
    return __builtin_amdgcn_mfma_scale_f32_32x32x64_f8f6f4(
        a, b, c, 0, 0, 0, 0x7F7F7F7Fu, 0, 0x7F7F7F7Fu);
}

#define VMWAIT(N) asm volatile("s_waitcnt vmcnt(" #N ")" ::: "memory")
#define RBAR()    asm volatile("s_barrier" ::: "memory")
#define SBAR()    __builtin_amdgcn_sched_barrier(0)
#define PRIO1()   __builtin_amdgcn_s_setprio(1)
#define PRIO0()   __builtin_amdgcn_s_setprio(0)

__global__ void init_kernel(unsigned* rowMaxBits, int* counts){
    int i = blockIdx.x * blockDim.x + threadIdx.x;
    if (i < MQ){ rowMaxBits[i] = 0u; counts[i] = 0; }
}

// fp32 -> fp8(e4m3), SPLIT-FRAGMENT layout (bank-conflict-free reads).
// Panel = 256 rows x 64 k = 8 rowblocks x 2048 B. Element (r,k):
// byte = (r>>5)*2048 + ((k>>4)&1)*1024 + ((k>>5)*32 + (r&31))*16 + (k&15).
// Lane l of a fragment reads 16 B at rowblock*2048 + l*16 and 16 B at
// +1024 + l*16: contiguous 1024-B wave reads -> zero conflicts.
__launch_bounds__(256)
__global__ void convert_tile_kernel(const float* __restrict__ Aq,
                                    const float* __restrict__ Bt,
                                    char* __restrict__ Af8,
                                    char* __restrict__ Bf8){
    const int bid = blockIdx.x;            // (4 + 782) * 24 half-panels
    const int rt  = bid / 24;
    const int kh  = bid - rt * 24;         // 0..23
    const int pan  = kh >> 1;
    const int half = kh & 1;               // khalf (32 k)
    const int tid = threadIdx.x;

    const float* src; char* dst; int rowBase, nRows;
    if (rt < 4){
        src = Aq; dst = Af8 + ((size_t)rt * NPAN + pan) * PANB;
        rowBase = rt * 256; nRows = MQ;
    } else {
        src = Bt; dst = Bf8 + ((size_t)(rt - 4) * NPAN + pan) * PANB;
        rowBase = (rt - 4) * 256; nRows = NTRAIN;
    }

    __shared__ unsigned tile[2048];   // 8 KB

    #pragma unroll
    for (int i = 0; i < 8; ++i){
        int idx = i * 256 + tid;           // float4 unit, 0..2047
        int r   = idx >> 3;                // 0..255
        int c4  = idx & 7;                 // float4 col within 32-k half
        int grow = rowBase + r;
        float4 v = make_float4(0.f, 0.f, 0.f, 0.f);
        if (grow < nRows)
            v = *reinterpret_cast<const float4*>(
                src + (size_t)grow * KDIM + pan * 64 + half * 32 + c4 * 4);
        int p = 0;
        p = __builtin_amdgcn_cvt_pk_fp8_f32(v.x, v.y, p, false);
        p = __builtin_amdgcn_cvt_pk_fp8_f32(v.z, v.w, p, true);
        int word = (r >> 5) * 256 + (c4 >> 2) * 128 + (r & 31) * 4 + (c4 & 3);
        tile[word] = (unsigned)p;
    }
    __syncthreads();
    #pragma unroll
    for (int i = 0; i < 2; ++i){
        int c = i * 256 + tid;             // 16B chunk, 0..511
        int rowblock = c >> 6, rem = c & 63, jh = rem >> 5, row = rem & 31;
        size_t off = (size_t)rowblock * 2048 + (size_t)jh * 1024
                   + (size_t)half * 512 + (size_t)row * 16;
        *reinterpret_cast<i32x4*>(dst + off) =
            *reinterpret_cast<const i32x4*>((const char*)tile + c * 16);
    }
}

// 256x256 tile, 16 WAVES (4 wr x 4 wc, per-wave 64x64 -> acc 64 regs),
// FOUR waves/SIMD at 1 block/CU (128 KB LDS keeps the full reg grant;
// live set ~110). 4-buffer depth-2 counted-vmcnt, ONE barrier per panel;
// staging is wave-uniform (2 loads/thread/panel) -> VMWAIT(2).
// VERIFIED best: 515.7 us total (round 24).
__launch_bounds__(1024)
__global__ void gemm_fast_kernel(const char* __restrict__ Af8,
                                 const char* __restrict__ Bf8,
                                 unsigned* __restrict__ rowMaxBits,
                                 int* __restrict__ counts,
                                 int* __restrict__ cands){
    const int g    = blockIdx.x;                 // 3128 = 8 * 391
    const int wgid = (g & 7) * 391 + (g >> 3);   // bijective XCD chunking
    const int mt   = wgid & 3;
    const int nt   = wgid >> 2;
    const int tid  = threadIdx.x;
    const int lane = tid & 63;
    const int wave = tid >> 6;       // 0..15
    const int wr   = wave >> 2;      // 0..3  rows wr*64
    const int wc   = wave & 3;       // 0..3  cols wc*64
    const int lh   = lane >> 5;
    const int lm   = lane & 31;

    __shared__ union {
        char stg[4][2][PANB];                         // 128 KB staging
        struct { float redmax[256][4]; float ths[256]; } ep;
    } sm;

    const char* Apan = Af8 + (size_t)mt * NPAN * PANB;
    const char* Bpan = Bf8 + (size_t)nt * NPAN * PANB;

    f32x16 acc[2][2];
    #pragma unroll
    for (int i = 0; i < 2; ++i)
        #pragma unroll
        for (int j = 0; j < 2; ++j)
            #pragma unroll
            for (int q = 0; q < 16; ++q)
                acc[i][j][q] = 0.f;

    i32x8 aq0, aq1, bq0, bq1;

    auto stageAB = [&](int t){
        const char* sa = Apan + (size_t)t * PANB;
        const char* sb = Bpan + (size_t)t * PANB;
        char* da = &sm.stg[t & 3][0][0];
        char* db = &sm.stg[t & 3][1][0];
        gload_lds16(sa + tid * 16, da + tid * 16);   // A: 1024 chunks
        gload_lds16(sb + tid * 16, db + tid * 16);   // B: 1024 chunks
    };

#define LD_FRAG(V, AB, T, F) { \
    const char* b_ = &sm.stg[(T) & 3][AB][(F) * 2048]; \
    i32x4 lo_ = *reinterpret_cast<const i32x4*>(b_ + lane * 16); \
    i32x4 hi_ = *reinterpret_cast<const i32x4*>(b_ + 1024 + lane * 16); \
    V = __builtin_shufflevector(lo_, hi_, 0, 1, 2, 3, 4, 5, 6, 7); }

#define PANEL(T, STAGE, WAITCODE) { \
    LD_FRAG(bq0, 1, T, wc * 2 + 0); \
    LD_FRAG(bq1, 1, T, wc * 2 + 1); \
    LD_FRAG(aq0, 0, T, wr * 2 + 0); \
    LD_FRAG(aq1, 0, T, wr * 2 + 1); \
    STAGE; \
    SBAR(); \
    PRIO1(); \
    acc[0][0] = mfma_fp8(aq0, bq0, acc[0][0]); \
    acc[0][1] = mfma_fp8(aq0, bq1, acc[0][1]); \
    acc[1][0] = mfma_fp8(aq1, bq0, acc[1][0]); \
    acc[1][1] = mfma_fp8(aq1, bq1, acc[1][1]); \
    PRIO0(); SBAR(); \
    WAITCODE; }

    // prologue: panels 0,1 staged (4 loads); drain panel 0, keep panel 1
    stageAB(0); stageAB(1);
    VMWAIT(2);
    RBAR();

    #pragma unroll 2
    for (int t = 0; t < NPAN - 2; ++t){
        PANEL(t, stageAB(t + 2), { VMWAIT(2); RBAR(); });
    }
    PANEL(NPAN - 2, (void)0, { VMWAIT(0); RBAR(); });
    PANEL(NPAN - 1, (void)0, (void)0);
#undef PANEL
#undef LD_FRAG

    // ---- epilogue: cross-wc row-max reduce, 1 atomicMax/row, collect ----
    __syncthreads();
    #pragma unroll
    for (int rf = 0; rf < 2; ++rf)
        #pragma unroll
        for (int q = 0; q < 16; ++q){
            float v = fmaxf(acc[rf][0][q], acc[rf][1][q]);
            v = fmaxf(v, __shfl_xor(v, 1));
            v = fmaxf(v, __shfl_xor(v, 2));
            v = fmaxf(v, __shfl_xor(v, 4));
            v = fmaxf(v, __shfl_xor(v, 8));
            v = fmaxf(v, __shfl_xor(v, 16));
            if (lm == 0){
                int row = wr * 64 + rf * 32 + (q & 3) + 8 * (q >> 2) + 4 * lh;
                sm.ep.redmax[row][wc] = v;
            }
        }
    __syncthreads();
    if (tid < 256){
        float m = fmaxf(fmaxf(sm.ep.redmax[tid][0], sm.ep.redmax[tid][1]),
                        fmaxf(sm.ep.redmax[tid][2], sm.ep.redmax[tid][3]));
        unsigned old = atomicMax(&rowMaxBits[mt * 256 + tid], encf(m));
        sm.ep.ths[tid] = fmaxf(m, decf(old)) - DELTA;
    }
    __syncthreads();
    #pragma unroll
    for (int rf = 0; rf < 2; ++rf)
        #pragma unroll
        for (int q = 0; q < 16; ++q){
            int row = wr * 64 + rf * 32 + (q & 3) + 8 * (q >> 2) + 4 * lh;
            float thr = sm.ep.ths[row];
            #pragma unroll
            for (int cf = 0; cf < 2; ++cf){
                if (acc[rf][cf][q] >= thr){
                    int gcol = nt * 256 + wc * 64 + cf * 32 + lm;
                    if (gcol < NTRAIN){
                        int grow = mt * 256 + row;
                        int slot = atomicAdd(&counts[grow], 1);
                        if (slot < CAP) cands[(size_t)grow * CAP + slot] = gcol;
                    }
                }
            }
        }
}

// ---- fallback GEMM (round-0 path, used only if ws too small) ----
__launch_bounds__(256)
__global__ void gemm_collect_kernel(const float* __restrict__ Aq,
                                    const float* __restrict__ Bt,
                                    unsigned* __restrict__ rowMaxBits,
                                    int* __restrict__ counts,
                                    int* __restrict__ cands){
    const int m0 = blockIdx.x * 128;
    const int n0 = blockIdx.y * 128;
    const int tid  = threadIdx.x;
    const int lane = tid & 63;
    const int wave = tid >> 6;
    const int wm = (wave >> 1) * 64;
    const int wn = (wave & 1) * 64;

    __shared__ union {
        struct { ushort As[128][32]; ushort Bs[128][32]; } s;
        float Csh[64][129];
    } sm;

    f32x4 acc[4][4];
    #pragma unroll
    for (int i = 0; i < 4; ++i)
        #pragma unroll
        for (int j = 0; j < 4; ++j)
            acc[i][j] = (f32x4){0.f, 0.f, 0.f, 0.f};

    const int fr = lane & 15;
    const int fg = lane >> 4;

    for (int kt = 0; kt < KDIM / 32; ++kt){
        const int k0 = kt * 32;
        __syncthreads();
        #pragma unroll
        for (int i = 0; i < 4; ++i){
            int f  = tid + i * 256;
            int r  = f >> 3;
            int kc = (f & 7) * 4;
            float4 av = *reinterpret_cast<const float4*>(Aq + (size_t)(m0 + r) * KDIM + k0 + kc);
            ushort4 ah; ah.x = cvt_bf16(av.x); ah.y = cvt_bf16(av.y);
            ah.z = cvt_bf16(av.z); ah.w = cvt_bf16(av.w);
            *reinterpret_cast<ushort4*>(&sm.s.As[r][kc]) = ah;
            int nr = n0 + r;
            float4 bv = make_float4(0.f, 0.f, 0.f, 0.f);
            if (nr < NTRAIN)
                bv = *reinterpret_cast<const float4*>(Bt + (size_t)nr * KDIM + k0 + kc);
            ushort4 bh; bh.x = cvt_bf16(bv.x); bh.y = cvt_bf16(bv.y);
            bh.z = cvt_bf16(bv.z); bh.w = cvt_bf16(bv.w);
            *reinterpret_cast<ushort4*>(&sm.s.Bs[r][kc]) = bh;
        }
        __syncthreads();
        s16x8 af[4], bfv[4];
        #pragma unroll
        for (int i = 0; i < 4; ++i){
            af[i]  = *reinterpret_cast<const s16x8*>(&sm.s.As[wm + i * 16 + fr][fg * 8]);
            bfv[i] = *reinterpret_cast<const s16x8*>(&sm.s.Bs[wn + i * 16 + fr][fg * 8]);
        }
        #pragma unroll
        for (int i = 0; i < 4; ++i)
            #pragma unroll
            for (int j = 0; j < 4; ++j)
                acc[i][j] = __builtin_amdgcn_mfma_f32_16x16x32_bf16(af[i], bfv[j], acc[i][j], 0, 0, 0);
    }

    for (int half = 0; half < 2; ++half){
        __syncthreads();
        if ((wave >> 1) == half){
            #pragma unroll
            for (int i = 0; i < 4; ++i)
                #pragma unroll
                for (int j = 0; j < 4; ++j)
                    #pragma unroll
                    for (int q = 0; q < 4; ++q){
                        int rr = i * 16 + (lane >> 4) * 4 + q;
                        int cc = wn + j * 16 + (lane & 15);
                        sm.Csh[rr][cc] = acc[i][j][q];
                    }
        }
        __syncthreads();
        if (tid < 64){
            int grow = m0 + half * 64 + tid;
            float mx = -1e30f;
            #pragma unroll 4
            for (int c = 0; c < 128; ++c) mx = fmaxf(mx, sm.Csh[tid][c]);
            unsigned old = atomicMax(&rowMaxBits[grow], encf(mx));
            float gmax = fmaxf(mx, decf(old));
            float thr = gmax - DELTA;
            for (int c = 0; c < 128; ++c){
                int gcol = n0 + c;
                if (gcol < NTRAIN && sm.Csh[tid][c] >= thr){
                    int slot = atomicAdd(&counts[grow], 1);
                    if (slot < CAP) cands[(size_t)grow * CAP + slot] = gcol;
                }
            }
        }
    }
}

// one block per query row: exact fp32 rescore, top-KSEL, softmax, output.
__launch_bounds__(256)
__global__ void rescore_output_kernel(const float* __restrict__ Aq,
                                      const float* __restrict__ Bt,
                                      const int* __restrict__ labels,
                                      const int* __restrict__ counts,
                                      const int* __restrict__ cands,
                                      float* __restrict__ out){
    const int row  = blockIdx.x;
    const int tid  = threadIdx.x;
    const int lane = tid & 63;
    const int wave = tid >> 6;

    __shared__ float q[KDIM];
    __shared__ float sv[CAP];
    __shared__ float rv[256];
    __shared__ int   ri[256];
    __shared__ float topS[KSEL];
    __shared__ int   topI[KSEL];
    __shared__ float cls[3][NCLS];

    for (int k = tid; k < KDIM; k += 256) q[k] = Aq[(size_t)row * KDIM + k];
    int m = counts[row]; if (m > CAP) m = CAP;
    __syncthreads();

    for (int c = wave; c < m; c += 4){
        int idx = cands[(size_t)row * CAP + c];
        const float* b = Bt + (size_t)idx * KDIM;
        float s = 0.f;
        #pragma unroll
        for (int u = 0; u < 12; ++u){
            int k = lane * 12 + u;
            s += q[k] * b[k];
        }
        #pragma unroll
        for (int off = 32; off; off >>= 1) s += __shfl_down(s, off);
        if (lane == 0) sv[c] = s;
    }
    __syncthreads();

    int msel = m < KSEL ? m : KSEL;
    for (int j = 0; j < msel; ++j){
        float bs = -1e30f; int bi = 0x7FFFFFFF;
        for (int c = tid; c < m; c += 256){
            float v = sv[c];
            if (v > bs){ bs = v; bi = c; }
        }
        rv[tid] = bs; ri[tid] = bi;
        __syncthreads();
        for (int st = 128; st; st >>= 1){
            if (tid < st){
                if (rv[tid + st] > rv[tid] ||
                    (rv[tid + st] == rv[tid] && ri[tid + st] < ri[tid])){
                    rv[tid] = rv[tid + st]; ri[tid] = ri[tid + st];
                }
            }
            __syncthreads();
        }
        if (tid == 0){
            topS[j] = rv[0];
            topI[j] = cands[(size_t)row * CAP + ri[0]];
            sv[ri[0]] = -1e30f;
        }
        __syncthreads();
    }

    for (int i = tid; i < 3 * NCLS; i += 256) (&cls[0][0])[i] = 0.f;
    __syncthreads();

    if (tid == 0){
        float s0 = topS[0];
        float e[KSEL];
        float Z = 0.f;
        for (int j = 0; j < msel; ++j){ e[j] = __expf((topS[j] - s0) * TINV); Z += e[j]; }
        float inv = 1.f / Z;
        for (int j = 0; j < msel; ++j){
            int lb = labels[topI[j]];
            float w = e[j] * inv;
            if (j < 10) cls[0][lb] += w;
            if (j < 50) cls[1][lb] += w;
            cls[2][lb] += w;
        }
    }
    __syncthreads();

    for (int c = tid; c < NCLS; c += 256){
        out[(size_t)row * NCLS + c]                         = cls[0][c];
        out[(size_t)MQ * NCLS + (size_t)row * NCLS + c]     = cls[1][c];
        out[(size_t)2 * MQ * NCLS + (size_t)row * NCLS + c] = cls[2][c];
    }
}

extern "C" void kernel_launch(void* const* d_in, const int* in_sizes, int n_in,
                              void* d_out, int out_size, void* d_ws, size_t ws_size,
                              hipStream_t stream){
    const float* Aq     = (const float*)d_in[0];
    const float* Bt     = (const float*)d_in[1];
    const int*   labels = (const int*)d_in[2];
    float* out = (float*)d_out;

    char* ws = (char*)d_ws;
    unsigned* rowMaxBits = (unsigned*)ws;                         // MQ u32
    int*      counts     = (int*)(ws + (size_t)MQ * 4);           // MQ i32
    int*      cands      = (int*)(ws + (size_t)MQ * 8);           // MQ*CAP i32
    char*     Af8        = ws + (size_t)MQ * 8 + (size_t)MQ * CAP * 4;
    char*     Bf8        = Af8 + (size_t)4 * NPAN * PANB;

    const size_t need = (size_t)MQ * 8 + (size_t)MQ * CAP * 4
                      + (size_t)(4 + NT256) * NPAN * PANB;

    hipLaunchKernelGGL(init_kernel, dim3(4), dim3(256), 0, stream, rowMaxBits, counts);

    if (ws_size >= need){
        hipLaunchKernelGGL(convert_tile_kernel, dim3((4 + NT256) * 24), dim3(256), 0, stream,
                           Aq, Bt, Af8, Bf8);
        hipLaunchKernelGGL(gemm_fast_kernel, dim3(8 * 391), dim3(1024), 0, stream,
                           Af8, Bf8, rowMaxBits, counts, cands);
    } else {
        hipLaunchKernelGGL(gemm_collect_kernel, dim3(8, (NTRAIN + 127) / 128), dim3(256), 0, stream,
                           Aq, Bt, rowMaxBits, counts, cands);
    }
    hipLaunchKernelGGL(rescore_output_kernel, dim3(MQ), dim3(256), 0, stream,
                       Aq, Bt, labels, counts, cands, out);
}